// Round 4
// baseline (250.530 us; speedup 1.0000x reference)
//
#include <hip/hip_runtime.h>
#include <math.h>

#define EDIM 768
#define NH 12
#define HD 64
#define BSZ 8
#define NN 512
#define NCAT 1664          // 768(q) + 768(k) + 36(vw) padded to 13*128

typedef short short8 __attribute__((ext_vector_type(8)));
typedef float f32x4 __attribute__((ext_vector_type(4)));

__device__ __forceinline__ unsigned short f2bf(float x) {
    unsigned int u = __float_as_uint(x);
    u = (u + 0x7FFF + ((u >> 16) & 1)) >> 16;   // RNE
    return (unsigned short)u;
}
__device__ __forceinline__ void gl2lds16(const void* g, void* l) {
    __builtin_amdgcn_global_load_lds(
        (const __attribute__((address_space(1))) unsigned int*)g,
        (__attribute__((address_space(3))) unsigned int*)l, 16, 0, 0);
}

// ---- prep block ranges ----
#define PB_TR_END   1152         // WT transpose for q/k (48 n-tiles x 24 e-tiles)
#define PB_VW_END   1260         // +108: WT vw columns (36*768/256)
#define PB_CVT_END  2028         // +768: X fp32->bf16 (2 units/thread)
#define PB_BC_END   2035         // +7: bcat
#define PREP_BLOCKS 2070         // +35: WT padding rows zero

// ---------------- K1: fused prep ----------------
__global__ __launch_bounds__(256) void k_prep(
        const float* __restrict__ query,
        const float* __restrict__ Wq, const float* __restrict__ bq,
        const float* __restrict__ Wk, const float* __restrict__ bk,
        const float* __restrict__ Wv, const float* __restrict__ bv,
        const float* __restrict__ W1, const float* __restrict__ W2,
        const float* __restrict__ W3,
        unsigned short* __restrict__ WT, float* __restrict__ bcat,
        unsigned short* __restrict__ Xb) {
    __shared__ float sm[1536];
    const int bid = blockIdx.x;
    const int t = threadIdx.x;

    if (bid < PB_TR_END) {
        // WT[n][e] = W{q,k}[e][n mod 768] bf16 (q-part pre-scaled by 0.125)
        float (*tile)[33] = (float(*)[33])sm;
        const int n0 = (bid % 48) * 32, e0 = (bid / 48) * 32;
        const float* src = (n0 < 768) ? Wq : Wk;
        const float sc = (n0 < 768) ? 0.125f : 1.0f;
        const int ol0 = (n0 < 768) ? n0 : (n0 - 768);
        const int tx = t & 31, ty = t >> 5;
        #pragma unroll
        for (int s = 0; s < 4; s++)
            tile[ty + s * 8][tx] = src[(size_t)(e0 + ty + s * 8) * EDIM + ol0 + tx];
        __syncthreads();
        #pragma unroll
        for (int s = 0; s < 4; s++)
            WT[(size_t)(n0 + ty + s * 8) * EDIM + e0 + tx] = f2bf(tile[tx][ty + s * 8] * sc);
    } else if (bid < PB_VW_END) {
        // WT vw columns: WT[1536+o2][e] = sum_d Wv[e][h*64+d]*Wc[h*64+d]
        int idx = (bid - PB_TR_END) * 256 + t;   // < 27648
        int o2 = idx / 768, e = idx - o2 * 768;
        int h = o2 / 3, c = o2 - (o2 / 3) * 3;
        const float* Wc = (c == 0) ? W1 : (c == 1) ? W2 : W3;
        const float4* wvp = (const float4*)(Wv + (size_t)e * EDIM + h * HD);
        const float4* wcp = (const float4*)(Wc + h * HD);
        float s = 0.f;
        #pragma unroll
        for (int d4 = 0; d4 < 16; d4++) {
            float4 a = wvp[d4], b = wcp[d4];
            s += a.x * b.x + a.y * b.y + a.z * b.z + a.w * b.w;
        }
        WT[(size_t)(1536 + o2) * EDIM + e] = f2bf(s);
    } else if (bid < PB_CVT_END) {
        // X fp32 (n,b,e) -> Xb[m][e] bf16; 2 units per thread (half-split)
        int base = (bid - PB_VW_END) * 256 + t;   // < 196608
        #pragma unroll
        for (int half = 0; half < 2; half++) {
            int idx = base + half * 196608;
            int m = idx / 96, e8 = (idx - (idx / 96) * 96) * 8;
            int b = m >> 9, i = m & (NN - 1);
            const float* src = query + ((size_t)i * BSZ + b) * EDIM + e8;
            float4 v0 = *(const float4*)src;
            float4 v1 = *(const float4*)(src + 4);
            unsigned int p0 = f2bf(v0.x) | ((unsigned int)f2bf(v0.y) << 16);
            unsigned int p1 = f2bf(v0.z) | ((unsigned int)f2bf(v0.w) << 16);
            unsigned int p2 = f2bf(v1.x) | ((unsigned int)f2bf(v1.y) << 16);
            unsigned int p3 = f2bf(v1.z) | ((unsigned int)f2bf(v1.w) << 16);
            uint4 pk = {p0, p1, p2, p3};
            *(uint4*)&Xb[(size_t)idx * 8] = pk;
        }
    } else if (bid < PB_BC_END) {
        int o = (bid - PB_CVT_END) * 256 + t;
        if (o < NCAT) {
            float v = 0.f;
            if (o < 768) v = bq[o] * 0.125f;
            else if (o < 1536) v = bk[o - 768];
            else if (o < 1572) {
                int o2 = o - 1536;
                int h = o2 / 3, c = o2 - (o2 / 3) * 3;
                const float* Wc = (c == 0) ? W1 : (c == 1) ? W2 : W3;
                float s = 0.f;
                for (int d = 0; d < HD; d++) s += bv[h * HD + d] * Wc[h * HD + d];
                v = s;
            }
            bcat[o] = v;
        }
    } else {
        int tid = (bid - PB_BC_END) * 256 + t;
        if (tid < 8832) {
            uint4 z = {0, 0, 0, 0};
            *(uint4*)&WT[(size_t)1572 * EDIM + (size_t)tid * 8] = z;
        }
    }
}

// ---------------- K2: bf16 MFMA GEMM (128x128 tile, m97 structure, XCD-swizzled grid) ----------------
// Grid: 416 = 32 m-panels x 13 n-panels = 8 XCDs x 52. Each XCD owns 4 contiguous
// m-panels x all 13 n-panels: working set = 4x196KB (Xb rows) + 2.6MB (WT) = 3.4MB < 4MB L2.
__global__ __launch_bounds__(256) void k_gemm_qkv(
        const unsigned short* __restrict__ Xb, const unsigned short* __restrict__ WT,
        const float* __restrict__ bcat,
        unsigned short* __restrict__ qb, unsigned short* __restrict__ kb,
        float* __restrict__ vwb) {
    __shared__ short As[8 * 128 * 8];   // 16 KB  [kgroup][row][8]
    __shared__ short Bs[8 * 128 * 8];   // 16 KB
    const int t = threadIdx.x;
    const int bx = blockIdx.x;
    const int wg = (bx & 7) * 52 + (bx >> 3);        // bijective: 416 = 8*52
    const int m0 = (wg / 13) * 128, n0 = (wg % 13) * 128;
    const int w = t >> 6, lane = t & 63, quad = lane >> 4, ln = lane & 15;
    const int wr = (w & 1) * 64, wc = (w >> 1) * 64;

    f32x4 acc[4][4];
    #pragma unroll
    for (int mi = 0; mi < 4; mi++)
        #pragma unroll
        for (int ni = 0; ni < 4; ni++) acc[mi][ni] = (f32x4){0.f, 0.f, 0.f, 0.f};

    for (int k0 = 0; k0 < EDIM; k0 += 64) {
        __syncthreads();
        #pragma unroll
        for (int is = 0; is < 4; is++) {
            int slot = is * 256 + t;
            int g = slot >> 7, m = slot & 127;
            gl2lds16(Xb + (size_t)(m0 + m) * EDIM + k0 + g * 8, &As[(size_t)(is * 256 + w * 64) * 8]);
        }
        #pragma unroll
        for (int is = 0; is < 4; is++) {
            int slot = is * 256 + t;
            int g = slot >> 7, n = slot & 127;
            gl2lds16(WT + (size_t)(n0 + n) * EDIM + k0 + g * 8, &Bs[(size_t)(is * 256 + w * 64) * 8]);
        }
        __syncthreads();
        #pragma unroll
        for (int s = 0; s < 2; s++) {
            short8 af[4], bf[4];
            #pragma unroll
            for (int mi = 0; mi < 4; mi++)
                af[mi] = *(const short8*)&As[(size_t)((s * 4 + quad) * 128 + wr + mi * 16 + ln) * 8];
            #pragma unroll
            for (int ni = 0; ni < 4; ni++)
                bf[ni] = *(const short8*)&Bs[(size_t)((s * 4 + quad) * 128 + wc + ni * 16 + ln) * 8];
            #pragma unroll
            for (int mi = 0; mi < 4; mi++)
                #pragma unroll
                for (int ni = 0; ni < 4; ni++)
                    acc[mi][ni] = __builtin_amdgcn_mfma_f32_16x16x32_bf16(af[mi], bf[ni], acc[mi][ni], 0, 0, 0);
        }
    }

    #pragma unroll
    for (int mi = 0; mi < 4; mi++) {
        #pragma unroll
        for (int r = 0; r < 4; r++) {
            int mg = m0 + wr + mi * 16 + quad * 4 + r;
            int b_ = mg >> 9, i_ = mg & (NN - 1);
            #pragma unroll
            for (int ni = 0; ni < 4; ni++) {
                int o = n0 + wc + ni * 16 + ln;
                float val = acc[mi][ni][r] + bcat[o];
                if (o < 768) {
                    int h = o >> 6, d = o & 63;
                    qb[(((size_t)b_ * NH + h) * NN + i_) * HD + d] = f2bf(val);  // scale folded into WT/bcat
                } else if (o < 1536) {
                    int o2 = o - 768;
                    int h = o2 >> 6, d = o2 & 63;
                    kb[(((size_t)b_ * NH + h) * NN + i_) * HD + d] = f2bf(val);
                } else if (o < 1572) {
                    int o2 = o - 1536;
                    int h = o2 / 3, c = o2 - (o2 / 3) * 3;
                    vwb[(((size_t)b_ * NH + h) * NN + i_) * 3 + c] = val;
                }
            }
        }
    }
}

// ---------------- K3: attention partials — async K staging (gl2lds), 8 blocks/CU ----------------
__global__ __launch_bounds__(256, 8) void k_attn(
        const unsigned short* __restrict__ qb, const unsigned short* __restrict__ kb,
        const float* __restrict__ vwb, const float* __restrict__ bias,
        const float* __restrict__ pos,
        float* __restrict__ mp, float* __restrict__ lp,
        float* __restrict__ a0p, float* __restrict__ a1p, float* __restrict__ a2p) {
    __shared__ uint4 Ks[128 * 8];   // 16 KB; slot (r,s) holds K col s^(r&7)
    __shared__ float ws0[128], ws1[128], ws2[128];
    __shared__ float pjx[128], pjy[128], pjz[128];
    __shared__ float pix[64], piy[64], piz[64];

    const int t = threadIdx.x;
    const int bid = blockIdx.x;
    const int h = bid % NH;
    const int r1 = bid / NH;            // [0,256)
    const int js = r1 & 3;
    const int it = (r1 >> 2) & 7;
    const int b = r1 >> 5;
    const int i0 = it * 64;
    const int jb = js * 128;
    const int w = t >> 6, lane = t & 63, quad = lane >> 4, ln = lane & 15;
    const size_t bh = (size_t)b * NH + h;

    // ---- K tile (128x64 bf16): async global->LDS, linear dest + involution-swizzled source ----
    const char* kbase = (const char*)(kb + (bh * NN + jb) * HD);   // row stride 128 B
    #pragma unroll
    for (int is = 0; is < 4; is++) {
        int unit = is * 256 + w * 64 + lane;
        int rl = unit >> 3, cc = unit & 7;
        gl2lds16(kbase + (size_t)rl * 128 + ((cc ^ (rl & 7)) << 4), &Ks[is * 256 + w * 64]);
    }

    // ---- vw loads ----
    float wv0 = vwb[bh * (NN * 3) + (size_t)jb * 3 + t];
    float wv1 = (t < 128) ? vwb[bh * (NN * 3) + (size_t)jb * 3 + 256 + t] : 0.f;

    // ---- q fragments straight from global (A-frag = 16 contiguous bytes) ----
    const unsigned short* qrow = qb + (bh * NN + i0 + w * 16 + ln) * HD;
    short8 a0f = *(const short8*)(qrow + quad * 8);
    short8 a1f = *(const short8*)(qrow + 32 + quad * 8);

    // ---- bias straight into MFMA accumulators (coalesced: 16 lanes x 4 rows) ----
    const float* bbase = bias + (bh * NN + i0 + w * 16 + quad * 4) * NN + jb + ln;
    f32x4 acc[8];
    #pragma unroll
    for (int jsub = 0; jsub < 8; jsub++)
        #pragma unroll
        for (int r = 0; r < 4; r++)
            acc[jsub][r] = bbase[r * NN + jsub * 16];

    // ---- position staging ----
    for (int idx = t; idx < 384; idx += 256) {
        float pv = pos[((size_t)b * NN + jb) * 3 + idx];
        int jj = idx / 3, c = idx - (idx / 3) * 3;
        if (c == 0) pjx[jj] = pv; else if (c == 1) pjy[jj] = pv; else pjz[jj] = pv;
    }
    if (t < 192) {
        float pv = pos[((size_t)b * NN + i0) * 3 + t];
        int ii = t / 3, c = t - (t / 3) * 3;
        if (c == 0) pix[ii] = pv; else if (c == 1) piy[ii] = pv; else piz[ii] = pv;
    }

    // ---- vw scatter to LDS ----
    {
        int jj = t / 3, c = t - (t / 3) * 3;
        if (c == 0) ws0[jj] = wv0; else if (c == 1) ws1[jj] = wv0; else ws2[jj] = wv0;
        if (t < 128) {
            int t2 = 256 + t;
            int jj2 = t2 / 3, c2 = t2 - (t2 / 3) * 3;
            if (c2 == 0) ws0[jj2] = wv1; else if (c2 == 1) ws1[jj2] = wv1; else ws2[jj2] = wv1;
        }
    }
    __syncthreads();   // drains gl2lds (vmcnt) + LDS writes

    // ---- MFMA: D = Q·K^T ----
    #pragma unroll
    for (int jsub = 0; jsub < 8; jsub++) {
        int krow = jsub * 16 + ln;
        short8 b0f = *(const short8*)&Ks[krow * 8 + (quad ^ (krow & 7))];
        short8 b1f = *(const short8*)&Ks[krow * 8 + ((quad + 4) ^ (krow & 7))];
        acc[jsub] = __builtin_amdgcn_mfma_f32_16x16x32_bf16(a0f, b0f, acc[jsub], 0, 0, 0);
        acc[jsub] = __builtin_amdgcn_mfma_f32_16x16x32_bf16(a1f, b1f, acc[jsub], 0, 0, 0);
    }

    // ---- wave-wide max (any consistent m is valid with the exact slot merge) ----
    float m_r = acc[0][0];
    #pragma unroll
    for (int jsub = 0; jsub < 8; jsub++)
        #pragma unroll
        for (int r = 0; r < 4; r++) m_r = fmaxf(m_r, acc[jsub][r]);
    #pragma unroll
    for (int off = 1; off < 64; off <<= 1) m_r = fmaxf(m_r, __shfl_xor(m_r, off, 64));

    // ---- exp + geometry-on-the-fly weighted accumulate ----
    const int irbase = w * 16 + quad * 4;
    float lr[4] = {0.f, 0.f, 0.f, 0.f};
    float A0[4] = {0.f, 0.f, 0.f, 0.f};
    float A1[4] = {0.f, 0.f, 0.f, 0.f};
    float A2[4] = {0.f, 0.f, 0.f, 0.f};
    #pragma unroll
    for (int jsub = 0; jsub < 8; jsub++) {
        const int jl = jsub * 16 + ln;
        float w0 = ws0[jl], w1 = ws1[jl], w2 = ws2[jl];
        float px = pjx[jl], py = pjy[jl], pz = pjz[jl];
        #pragma unroll
        for (int r = 0; r < 4; r++) {
            float dx = px - pix[irbase + r];
            float dy = py - piy[irbase + r];
            float dz = pz - piz[irbase + r];
            float d2 = fmaf(dx, dx, fmaf(dy, dy, dz * dz));
            float inv = __builtin_amdgcn_rcpf(__builtin_amdgcn_sqrtf(d2) + 1e-5f);
            float p = __expf(acc[jsub][r] - m_r);
            float pi = p * inv;
            lr[r] += p;
            A0[r] = fmaf(pi * dx, w0, A0[r]);
            A1[r] = fmaf(pi * dy, w1, A1[r]);
            A2[r] = fmaf(pi * dz, w2, A2[r]);
        }
    }

    // ---- reduce over ln (j) ----
    #pragma unroll
    for (int off = 1; off < 16; off <<= 1) {
        #pragma unroll
        for (int r = 0; r < 4; r++) {
            lr[r] += __shfl_xor(lr[r], off, 64);
            A0[r] += __shfl_xor(A0[r], off, 64);
            A1[r] += __shfl_xor(A1[r], off, 64);
            A2[r] += __shfl_xor(A2[r], off, 64);
        }
    }
    if (ln == 0) {
        #pragma unroll
        for (int r = 0; r < 4; r++) {
            int ig = i0 + irbase + r;
            size_t o4 = (bh * NN + ig) * 4 + js;
            mp[o4] = m_r; lp[o4] = lr[r];
            a0p[o4] = A0[r]; a1p[o4] = A1[r]; a2p[o4] = A2[r];
        }
    }
}

// ---------------- K4: finalize — thread per (b,i,h), LDS head-reduce, 256 blocks ----------------
__global__ __launch_bounds__(256) void k_finalize(
        const float* __restrict__ mp, const float* __restrict__ lp,
        const float* __restrict__ a0p, const float* __restrict__ a1p,
        const float* __restrict__ a2p,
        const float* __restrict__ b1, const float* __restrict__ b2,
        const float* __restrict__ b3, float* __restrict__ out) {
    __shared__ float red[NH][16][3];
    const int t = threadIdx.x;
    const int g0 = blockIdx.x * 16;        // 16 (b,i) rows per block
    const int b = g0 >> 9;
    const int i0 = g0 & (NN - 1);

    if (t < NH * 16) {
        int h = t >> 4, row = t & 15;      // consecutive t -> consecutive rows (coalesced)
        size_t base = (((size_t)b * NH + h) * NN + i0 + row) * 4;
        f32x4 mv = *(const f32x4*)&mp[base];
        f32x4 lv = *(const f32x4*)&lp[base];
        f32x4 A0 = *(const f32x4*)&a0p[base];
        f32x4 A1 = *(const f32x4*)&a1p[base];
        f32x4 A2 = *(const f32x4*)&a2p[base];
        float M = fmaxf(fmaxf(mv[0], mv[1]), fmaxf(mv[2], mv[3]));
        float L = 0.f, c0 = 0.f, c1 = 0.f, c2 = 0.f;
        #pragma unroll
        for (int js = 0; js < 4; js++) {
            float e = __expf(mv[js] - M);
            L = fmaf(e, lv[js], L);
            c0 = fmaf(e, A0[js], c0);
            c1 = fmaf(e, A1[js], c1);
            c2 = fmaf(e, A2[js], c2);
        }
        float inv = 1.f / L;
        red[h][row][0] = c0 * inv;
        red[h][row][1] = c1 * inv;
        red[h][row][2] = c2 * inv;
    }
    __syncthreads();
    if (t < 48) {
        int row = t / 3, c = t - row * 3;
        float s = 0.f;
        #pragma unroll
        for (int h = 0; h < NH; h++) s += red[h][row][c];
        const float* bb = (c == 0) ? b1 : (c == 1) ? b2 : b3;
        out[((size_t)g0 + row) * 3 + c] = s + bb[0];
    }
}

extern "C" void kernel_launch(void* const* d_in, const int* in_sizes, int n_in,
                              void* d_out, int out_size, void* d_ws, size_t ws_size,
                              hipStream_t stream) {
    const float* query = (const float*)d_in[0];
    const float* bias  = (const float*)d_in[1];
    const float* pos   = (const float*)d_in[2];
    const float* Wq = (const float*)d_in[3];
    const float* bq = (const float*)d_in[4];
    const float* Wk = (const float*)d_in[5];
    const float* bk = (const float*)d_in[6];
    const float* Wv = (const float*)d_in[7];
    const float* bv = (const float*)d_in[8];
    const float* W1 = (const float*)d_in[9];
    const float* b1 = (const float*)d_in[10];
    const float* W2 = (const float*)d_in[11];
    const float* b2 = (const float*)d_in[12];
    const float* W3 = (const float*)d_in[13];
    const float* b3 = (const float*)d_in[14];
    float* out = (float*)d_out;

    char* p = (char*)d_ws;
    unsigned short* WT = (unsigned short*)p; p += (size_t)NCAT * EDIM * 2;      // 2.6 MB
    float* bcat = (float*)p;                 p += (size_t)NCAT * 4;
    unsigned short* Xb = (unsigned short*)p; p += (size_t)BSZ * NN * EDIM * 2;  // 6.3 MB
    unsigned short* qb = (unsigned short*)p; p += (size_t)BSZ * NH * NN * HD * 2;
    unsigned short* kb = (unsigned short*)p; p += (size_t)BSZ * NH * NN * HD * 2;
    float* vwb = (float*)p;                  p += (size_t)BSZ * NH * NN * 3 * 4;
    const size_t PSZ = (size_t)BSZ * NH * NN * 4;   // partial slots (b,h,i,js)
    float* mp  = (float*)p; p += PSZ * 4;
    float* lp  = (float*)p; p += PSZ * 4;
    float* a0p = (float*)p; p += PSZ * 4;
    float* a1p = (float*)p; p += PSZ * 4;
    float* a2p = (float*)p; p += PSZ * 4;

    k_prep<<<PREP_BLOCKS, 256, 0, stream>>>(query, Wq, bq, Wk, bk, Wv, bv,
                                            W1, W2, W3, WT, bcat, Xb);
    k_gemm_qkv<<<416, 256, 0, stream>>>(Xb, WT, bcat, qb, kb, vwb);
    k_attn<<<BSZ * NH * 8 * 4, 256, 0, stream>>>(qb, kb, vwb, bias, pos,
                                                 mp, lp, a0p, a1p, a2p);
    k_finalize<<<BSZ * NN / 16, 256, 0, stream>>>(mp, lp, a0p, a1p, a2p, b1, b2, b3, out);
}

// Round 5
// 243.948 us; speedup vs baseline: 1.0270x; 1.0270x over previous
//
#include <hip/hip_runtime.h>
#include <math.h>

#define EDIM 768
#define NH 12
#define HD 64
#define BSZ 8
#define NN 512
#define NCAT 1664          // 768(q) + 768(k) + 36(vw) padded to 13*128

typedef short short8 __attribute__((ext_vector_type(8)));
typedef float f32x4 __attribute__((ext_vector_type(4)));

__device__ __forceinline__ unsigned short f2bf(float x) {
    unsigned int u = __float_as_uint(x);
    u = (u + 0x7FFF + ((u >> 16) & 1)) >> 16;   // RNE
    return (unsigned short)u;
}
__device__ __forceinline__ void gl2lds16(const void* g, void* l) {
    __builtin_amdgcn_global_load_lds(
        (const __attribute__((address_space(1))) unsigned int*)g,
        (__attribute__((address_space(3))) unsigned int*)l, 16, 0, 0);
}

// ---- prep block ranges ----
#define PB_TR_END   1152         // WT transpose for q/k (48 n-tiles x 24 e-tiles)
#define PB_VW_END   1260         // +108: WT vw columns (36*768/256)
#define PB_CVT_END  2028         // +768: X fp32->bf16 (2 units/thread)
#define PB_BC_END   2035         // +7: bcat
#define PREP_BLOCKS 2070         // +35: WT padding rows zero

// ---------------- K1: fused prep ----------------
__global__ __launch_bounds__(256) void k_prep(
        const float* __restrict__ query,
        const float* __restrict__ Wq, const float* __restrict__ bq,
        const float* __restrict__ Wk, const float* __restrict__ bk,
        const float* __restrict__ Wv, const float* __restrict__ bv,
        const float* __restrict__ W1, const float* __restrict__ W2,
        const float* __restrict__ W3,
        unsigned short* __restrict__ WT, float* __restrict__ bcat,
        unsigned short* __restrict__ Xb) {
    __shared__ float sm[1536];
    const int bid = blockIdx.x;
    const int t = threadIdx.x;

    if (bid < PB_TR_END) {
        // WT[n][e] = W{q,k}[e][n mod 768] bf16 (q-part pre-scaled by 0.125)
        float (*tile)[33] = (float(*)[33])sm;
        const int n0 = (bid % 48) * 32, e0 = (bid / 48) * 32;
        const float* src = (n0 < 768) ? Wq : Wk;
        const float sc = (n0 < 768) ? 0.125f : 1.0f;
        const int ol0 = (n0 < 768) ? n0 : (n0 - 768);
        const int tx = t & 31, ty = t >> 5;
        #pragma unroll
        for (int s = 0; s < 4; s++)
            tile[ty + s * 8][tx] = src[(size_t)(e0 + ty + s * 8) * EDIM + ol0 + tx];
        __syncthreads();
        #pragma unroll
        for (int s = 0; s < 4; s++)
            WT[(size_t)(n0 + ty + s * 8) * EDIM + e0 + tx] = f2bf(tile[tx][ty + s * 8] * sc);
    } else if (bid < PB_VW_END) {
        // WT vw columns: WT[1536+o2][e] = sum_d Wv[e][h*64+d]*Wc[h*64+d]
        int idx = (bid - PB_TR_END) * 256 + t;   // < 27648
        int o2 = idx / 768, e = idx - o2 * 768;
        int h = o2 / 3, c = o2 - (o2 / 3) * 3;
        const float* Wc = (c == 0) ? W1 : (c == 1) ? W2 : W3;
        const float4* wvp = (const float4*)(Wv + (size_t)e * EDIM + h * HD);
        const float4* wcp = (const float4*)(Wc + h * HD);
        float s = 0.f;
        #pragma unroll
        for (int d4 = 0; d4 < 16; d4++) {
            float4 a = wvp[d4], b = wcp[d4];
            s += a.x * b.x + a.y * b.y + a.z * b.z + a.w * b.w;
        }
        WT[(size_t)(1536 + o2) * EDIM + e] = f2bf(s);
    } else if (bid < PB_CVT_END) {
        // X fp32 (n,b,e) -> Xb[m][e] bf16; 2 units per thread (half-split)
        int base = (bid - PB_VW_END) * 256 + t;   // < 196608
        #pragma unroll
        for (int half = 0; half < 2; half++) {
            int idx = base + half * 196608;
            int m = idx / 96, e8 = (idx - (idx / 96) * 96) * 8;
            int b = m >> 9, i = m & (NN - 1);
            const float* src = query + ((size_t)i * BSZ + b) * EDIM + e8;
            float4 v0 = *(const float4*)src;
            float4 v1 = *(const float4*)(src + 4);
            unsigned int p0 = f2bf(v0.x) | ((unsigned int)f2bf(v0.y) << 16);
            unsigned int p1 = f2bf(v0.z) | ((unsigned int)f2bf(v0.w) << 16);
            unsigned int p2 = f2bf(v1.x) | ((unsigned int)f2bf(v1.y) << 16);
            unsigned int p3 = f2bf(v1.z) | ((unsigned int)f2bf(v1.w) << 16);
            uint4 pk = {p0, p1, p2, p3};
            *(uint4*)&Xb[(size_t)idx * 8] = pk;
        }
    } else if (bid < PB_BC_END) {
        int o = (bid - PB_CVT_END) * 256 + t;
        if (o < NCAT) {
            float v = 0.f;
            if (o < 768) v = bq[o] * 0.125f;
            else if (o < 1536) v = bk[o - 768];
            else if (o < 1572) {
                int o2 = o - 1536;
                int h = o2 / 3, c = o2 - (o2 / 3) * 3;
                const float* Wc = (c == 0) ? W1 : (c == 1) ? W2 : W3;
                float s = 0.f;
                for (int d = 0; d < HD; d++) s += bv[h * HD + d] * Wc[h * HD + d];
                v = s;
            }
            bcat[o] = v;
        }
    } else {
        int tid = (bid - PB_BC_END) * 256 + t;
        if (tid < 8832) {
            uint4 z = {0, 0, 0, 0};
            *(uint4*)&WT[(size_t)1572 * EDIM + (size_t)tid * 8] = z;
        }
    }
}

// ---------------- K2: bf16 MFMA GEMM (128x128 tile, m97 structure, XCD-swizzled grid) ----------------
// Grid: 416 = 32 m-panels x 13 n-panels = 8 XCDs x 52. Each XCD owns 4 contiguous
// m-panels x all 13 n-panels: working set = 4x196KB (Xb rows) + 2.6MB (WT) = 3.4MB < 4MB L2.
__global__ __launch_bounds__(256) void k_gemm_qkv(
        const unsigned short* __restrict__ Xb, const unsigned short* __restrict__ WT,
        const float* __restrict__ bcat,
        unsigned short* __restrict__ qb, unsigned short* __restrict__ kb,
        float* __restrict__ vwb) {
    __shared__ short As[8 * 128 * 8];   // 16 KB  [kgroup][row][8]
    __shared__ short Bs[8 * 128 * 8];   // 16 KB
    const int t = threadIdx.x;
    const int bx = blockIdx.x;
    const int wg = (bx & 7) * 52 + (bx >> 3);        // bijective: 416 = 8*52
    const int m0 = (wg / 13) * 128, n0 = (wg % 13) * 128;
    const int w = t >> 6, lane = t & 63, quad = lane >> 4, ln = lane & 15;
    const int wr = (w & 1) * 64, wc = (w >> 1) * 64;

    f32x4 acc[4][4];
    #pragma unroll
    for (int mi = 0; mi < 4; mi++)
        #pragma unroll
        for (int ni = 0; ni < 4; ni++) acc[mi][ni] = (f32x4){0.f, 0.f, 0.f, 0.f};

    for (int k0 = 0; k0 < EDIM; k0 += 64) {
        __syncthreads();
        #pragma unroll
        for (int is = 0; is < 4; is++) {
            int slot = is * 256 + t;
            int g = slot >> 7, m = slot & 127;
            gl2lds16(Xb + (size_t)(m0 + m) * EDIM + k0 + g * 8, &As[(size_t)(is * 256 + w * 64) * 8]);
        }
        #pragma unroll
        for (int is = 0; is < 4; is++) {
            int slot = is * 256 + t;
            int g = slot >> 7, n = slot & 127;
            gl2lds16(WT + (size_t)(n0 + n) * EDIM + k0 + g * 8, &Bs[(size_t)(is * 256 + w * 64) * 8]);
        }
        __syncthreads();
        #pragma unroll
        for (int s = 0; s < 2; s++) {
            short8 af[4], bf[4];
            #pragma unroll
            for (int mi = 0; mi < 4; mi++)
                af[mi] = *(const short8*)&As[(size_t)((s * 4 + quad) * 128 + wr + mi * 16 + ln) * 8];
            #pragma unroll
            for (int ni = 0; ni < 4; ni++)
                bf[ni] = *(const short8*)&Bs[(size_t)((s * 4 + quad) * 128 + wc + ni * 16 + ln) * 8];
            #pragma unroll
            for (int mi = 0; mi < 4; mi++)
                #pragma unroll
                for (int ni = 0; ni < 4; ni++)
                    acc[mi][ni] = __builtin_amdgcn_mfma_f32_16x16x32_bf16(af[mi], bf[ni], acc[mi][ni], 0, 0, 0);
        }
    }

    #pragma unroll
    for (int mi = 0; mi < 4; mi++) {
        #pragma unroll
        for (int r = 0; r < 4; r++) {
            int mg = m0 + wr + mi * 16 + quad * 4 + r;
            int b_ = mg >> 9, i_ = mg & (NN - 1);
            #pragma unroll
            for (int ni = 0; ni < 4; ni++) {
                int o = n0 + wc + ni * 16 + ln;
                float val = acc[mi][ni][r] + bcat[o];
                if (o < 768) {
                    int h = o >> 6, d = o & 63;
                    qb[(((size_t)b_ * NH + h) * NN + i_) * HD + d] = f2bf(val);  // scale folded into WT/bcat
                } else if (o < 1536) {
                    int o2 = o - 768;
                    int h = o2 >> 6, d = o2 & 63;
                    kb[(((size_t)b_ * NH + h) * NN + i_) * HD + d] = f2bf(val);
                } else if (o < 1572) {
                    int o2 = o - 1536;
                    int h = o2 / 3, c = o2 - (o2 / 3) * 3;
                    vwb[(((size_t)b_ * NH + h) * NN + i_) * 3 + c] = val;
                }
            }
        }
    }
}

// ---------------- K3: attention partials — async K staging (gl2lds), 7 blocks/CU ----------------
__global__ __launch_bounds__(256, 7) void k_attn(
        const unsigned short* __restrict__ qb, const unsigned short* __restrict__ kb,
        const float* __restrict__ vwb, const float* __restrict__ bias,
        const float* __restrict__ pos,
        float* __restrict__ mp, float* __restrict__ lp,
        float* __restrict__ a0p, float* __restrict__ a1p, float* __restrict__ a2p) {
    __shared__ uint4 Ks[128 * 8];   // 16 KB; slot (r,s) holds K col s^(r&7)
    __shared__ float ws0[128], ws1[128], ws2[128];
    __shared__ float pjx[128], pjy[128], pjz[128];
    __shared__ float pix[64], piy[64], piz[64];

    const int t = threadIdx.x;
    const int bid = blockIdx.x;
    const int h = bid % NH;
    const int r1 = bid / NH;            // [0,256)
    const int js = r1 & 3;
    const int it = (r1 >> 2) & 7;
    const int b = r1 >> 5;
    const int i0 = it * 64;
    const int jb = js * 128;
    const int w = t >> 6, lane = t & 63, quad = lane >> 4, ln = lane & 15;
    const size_t bh = (size_t)b * NH + h;

    // ---- K tile (128x64 bf16): async global->LDS, linear dest + involution-swizzled source ----
    const char* kbase = (const char*)(kb + (bh * NN + jb) * HD);   // row stride 128 B
    #pragma unroll
    for (int is = 0; is < 4; is++) {
        int unit = is * 256 + w * 64 + lane;
        int rl = unit >> 3, cc = unit & 7;
        gl2lds16(kbase + (size_t)rl * 128 + ((cc ^ (rl & 7)) << 4), &Ks[is * 256 + w * 64]);
    }

    // ---- vw loads ----
    float wv0 = vwb[bh * (NN * 3) + (size_t)jb * 3 + t];
    float wv1 = (t < 128) ? vwb[bh * (NN * 3) + (size_t)jb * 3 + 256 + t] : 0.f;

    // ---- q fragments straight from global (A-frag = 16 contiguous bytes) ----
    const unsigned short* qrow = qb + (bh * NN + i0 + w * 16 + ln) * HD;
    short8 a0f = *(const short8*)(qrow + quad * 8);
    short8 a1f = *(const short8*)(qrow + 32 + quad * 8);

    // ---- bias straight into MFMA accumulators (coalesced: 16 lanes x 4 rows) ----
    const float* bbase = bias + (bh * NN + i0 + w * 16 + quad * 4) * NN + jb + ln;
    f32x4 acc[8];
    #pragma unroll
    for (int jsub = 0; jsub < 8; jsub++)
        #pragma unroll
        for (int r = 0; r < 4; r++)
            acc[jsub][r] = bbase[r * NN + jsub * 16];

    // ---- position staging ----
    for (int idx = t; idx < 384; idx += 256) {
        float pv = pos[((size_t)b * NN + jb) * 3 + idx];
        int jj = idx / 3, c = idx - (idx / 3) * 3;
        if (c == 0) pjx[jj] = pv; else if (c == 1) pjy[jj] = pv; else pjz[jj] = pv;
    }
    if (t < 192) {
        float pv = pos[((size_t)b * NN + i0) * 3 + t];
        int ii = t / 3, c = t - (t / 3) * 3;
        if (c == 0) pix[ii] = pv; else if (c == 1) piy[ii] = pv; else piz[ii] = pv;
    }

    // ---- vw scatter to LDS ----
    {
        int jj = t / 3, c = t - (t / 3) * 3;
        if (c == 0) ws0[jj] = wv0; else if (c == 1) ws1[jj] = wv0; else ws2[jj] = wv0;
        if (t < 128) {
            int t2 = 256 + t;
            int jj2 = t2 / 3, c2 = t2 - (t2 / 3) * 3;
            if (c2 == 0) ws0[jj2] = wv1; else if (c2 == 1) ws1[jj2] = wv1; else ws2[jj2] = wv1;
        }
    }
    __syncthreads();   // drains gl2lds (vmcnt) + LDS writes

    // ---- MFMA: D = Q·K^T ----
    #pragma unroll
    for (int jsub = 0; jsub < 8; jsub++) {
        int krow = jsub * 16 + ln;
        short8 b0f = *(const short8*)&Ks[krow * 8 + (quad ^ (krow & 7))];
        short8 b1f = *(const short8*)&Ks[krow * 8 + ((quad + 4) ^ (krow & 7))];
        acc[jsub] = __builtin_amdgcn_mfma_f32_16x16x32_bf16(a0f, b0f, acc[jsub], 0, 0, 0);
        acc[jsub] = __builtin_amdgcn_mfma_f32_16x16x32_bf16(a1f, b1f, acc[jsub], 0, 0, 0);
    }

    // ---- wave-wide max (any consistent m is valid with the exact slot merge) ----
    float m_r = acc[0][0];
    #pragma unroll
    for (int jsub = 0; jsub < 8; jsub++)
        #pragma unroll
        for (int r = 0; r < 4; r++) m_r = fmaxf(m_r, acc[jsub][r]);
    #pragma unroll
    for (int off = 1; off < 64; off <<= 1) m_r = fmaxf(m_r, __shfl_xor(m_r, off, 64));

    // ---- exp + geometry-on-the-fly weighted accumulate ----
    const int irbase = w * 16 + quad * 4;
    float lr[4] = {0.f, 0.f, 0.f, 0.f};
    float A0[4] = {0.f, 0.f, 0.f, 0.f};
    float A1[4] = {0.f, 0.f, 0.f, 0.f};
    float A2[4] = {0.f, 0.f, 0.f, 0.f};
    #pragma unroll
    for (int jsub = 0; jsub < 8; jsub++) {
        const int jl = jsub * 16 + ln;
        float w0 = ws0[jl], w1 = ws1[jl], w2 = ws2[jl];
        float px = pjx[jl], py = pjy[jl], pz = pjz[jl];
        #pragma unroll
        for (int r = 0; r < 4; r++) {
            float dx = px - pix[irbase + r];
            float dy = py - piy[irbase + r];
            float dz = pz - piz[irbase + r];
            float d2 = fmaf(dx, dx, fmaf(dy, dy, dz * dz));
            float inv = __builtin_amdgcn_rcpf(__builtin_amdgcn_sqrtf(d2) + 1e-5f);
            float p = __expf(acc[jsub][r] - m_r);
            float pi = p * inv;
            lr[r] += p;
            A0[r] = fmaf(pi * dx, w0, A0[r]);
            A1[r] = fmaf(pi * dy, w1, A1[r]);
            A2[r] = fmaf(pi * dz, w2, A2[r]);
        }
    }

    // ---- reduce over ln (j) ----
    #pragma unroll
    for (int off = 1; off < 16; off <<= 1) {
        #pragma unroll
        for (int r = 0; r < 4; r++) {
            lr[r] += __shfl_xor(lr[r], off, 64);
            A0[r] += __shfl_xor(A0[r], off, 64);
            A1[r] += __shfl_xor(A1[r], off, 64);
            A2[r] += __shfl_xor(A2[r], off, 64);
        }
    }
    if (ln == 0) {
        #pragma unroll
        for (int r = 0; r < 4; r++) {
            int ig = i0 + irbase + r;
            size_t o4 = (bh * NN + ig) * 4 + js;
            mp[o4] = m_r; lp[o4] = lr[r];
            a0p[o4] = A0[r]; a1p[o4] = A1[r]; a2p[o4] = A2[r];
        }
    }
}

// ---------------- K4: finalize — thread per (b,i,h), LDS head-reduce, 256 blocks ----------------
__global__ __launch_bounds__(256) void k_finalize(
        const float* __restrict__ mp, const float* __restrict__ lp,
        const float* __restrict__ a0p, const float* __restrict__ a1p,
        const float* __restrict__ a2p,
        const float* __restrict__ b1, const float* __restrict__ b2,
        const float* __restrict__ b3, float* __restrict__ out) {
    __shared__ float red[NH][16][3];
    const int t = threadIdx.x;
    const int g0 = blockIdx.x * 16;        // 16 (b,i) rows per block
    const int b = g0 >> 9;
    const int i0 = g0 & (NN - 1);

    if (t < NH * 16) {
        int h = t >> 4, row = t & 15;      // consecutive t -> consecutive rows (coalesced)
        size_t base = (((size_t)b * NH + h) * NN + i0 + row) * 4;
        f32x4 mv = *(const f32x4*)&mp[base];
        f32x4 lv = *(const f32x4*)&lp[base];
        f32x4 A0 = *(const f32x4*)&a0p[base];
        f32x4 A1 = *(const f32x4*)&a1p[base];
        f32x4 A2 = *(const f32x4*)&a2p[base];
        float M = fmaxf(fmaxf(mv[0], mv[1]), fmaxf(mv[2], mv[3]));
        float L = 0.f, c0 = 0.f, c1 = 0.f, c2 = 0.f;
        #pragma unroll
        for (int js = 0; js < 4; js++) {
            float e = __expf(mv[js] - M);
            L = fmaf(e, lv[js], L);
            c0 = fmaf(e, A0[js], c0);
            c1 = fmaf(e, A1[js], c1);
            c2 = fmaf(e, A2[js], c2);
        }
        float inv = 1.f / L;
        red[h][row][0] = c0 * inv;
        red[h][row][1] = c1 * inv;
        red[h][row][2] = c2 * inv;
    }
    __syncthreads();
    if (t < 48) {
        int row = t / 3, c = t - row * 3;
        float s = 0.f;
        #pragma unroll
        for (int h = 0; h < NH; h++) s += red[h][row][c];
        const float* bb = (c == 0) ? b1 : (c == 1) ? b2 : b3;
        out[((size_t)g0 + row) * 3 + c] = s + bb[0];
    }
}

extern "C" void kernel_launch(void* const* d_in, const int* in_sizes, int n_in,
                              void* d_out, int out_size, void* d_ws, size_t ws_size,
                              hipStream_t stream) {
    const float* query = (const float*)d_in[0];
    const float* bias  = (const float*)d_in[1];
    const float* pos   = (const float*)d_in[2];
    const float* Wq = (const float*)d_in[3];
    const float* bq = (const float*)d_in[4];
    const float* Wk = (const float*)d_in[5];
    const float* bk = (const float*)d_in[6];
    const float* Wv = (const float*)d_in[7];
    const float* bv = (const float*)d_in[8];
    const float* W1 = (const float*)d_in[9];
    const float* b1 = (const float*)d_in[10];
    const float* W2 = (const float*)d_in[11];
    const float* b2 = (const float*)d_in[12];
    const float* W3 = (const float*)d_in[13];
    const float* b3 = (const float*)d_in[14];
    float* out = (float*)d_out;

    char* p = (char*)d_ws;
    unsigned short* WT = (unsigned short*)p; p += (size_t)NCAT * EDIM * 2;      // 2.6 MB
    float* bcat = (float*)p;                 p += (size_t)NCAT * 4;
    unsigned short* Xb = (unsigned short*)p; p += (size_t)BSZ * NN * EDIM * 2;  // 6.3 MB
    unsigned short* qb = (unsigned short*)p; p += (size_t)BSZ * NH * NN * HD * 2;
    unsigned short* kb = (unsigned short*)p; p += (size_t)BSZ * NH * NN * HD * 2;
    float* vwb = (float*)p;                  p += (size_t)BSZ * NH * NN * 3 * 4;
    const size_t PSZ = (size_t)BSZ * NH * NN * 4;   // partial slots (b,h,i,js)
    float* mp  = (float*)p; p += PSZ * 4;
    float* lp  = (float*)p; p += PSZ * 4;
    float* a0p = (float*)p; p += PSZ * 4;
    float* a1p = (float*)p; p += PSZ * 4;
    float* a2p = (float*)p; p += PSZ * 4;

    k_prep<<<PREP_BLOCKS, 256, 0, stream>>>(query, Wq, bq, Wk, bk, Wv, bv,
                                            W1, W2, W3, WT, bcat, Xb);
    k_gemm_qkv<<<416, 256, 0, stream>>>(Xb, WT, bcat, qb, kb, vwb);
    k_attn<<<BSZ * NH * 8 * 4, 256, 0, stream>>>(qb, kb, vwb, bias, pos,
                                                 mp, lp, a0p, a1p, a2p);
    k_finalize<<<BSZ * NN / 16, 256, 0, stream>>>(mp, lp, a0p, a1p, a2p, b1, b2, b3, out);
}

// Round 6
// 233.550 us; speedup vs baseline: 1.0727x; 1.0445x over previous
//
#include <hip/hip_runtime.h>
#include <math.h>

#define EDIM 768
#define NH 12
#define HD 64
#define BSZ 8
#define NN 512
#define NCAT 1664          // 768(q) + 768(k) + 36(vw) padded to 13*128

typedef short short8 __attribute__((ext_vector_type(8)));
typedef float f32x4 __attribute__((ext_vector_type(4)));

__device__ __forceinline__ unsigned short f2bf(float x) {
    unsigned int u = __float_as_uint(x);
    u = (u + 0x7FFF + ((u >> 16) & 1)) >> 16;   // RNE
    return (unsigned short)u;
}
__device__ __forceinline__ void gl2lds16(const void* g, void* l) {
    __builtin_amdgcn_global_load_lds(
        (const __attribute__((address_space(1))) unsigned int*)g,
        (__attribute__((address_space(3))) unsigned int*)l, 16, 0, 0);
}

// ---- prep block ranges ----
#define PB_TR_END   1152         // WT transpose for q/k (48 n-tiles x 24 e-tiles)
#define PB_VW_END   1260         // +108: WT vw columns (36*768/256)
#define PB_CVT_END  2028         // +768: X fp32->bf16 (2 units/thread)
#define PB_BC_END   2035         // +7: bcat
#define PREP_BLOCKS 2070         // +35: WT padding rows zero

// ---------------- K1: fused prep ----------------
__global__ __launch_bounds__(256) void k_prep(
        const float* __restrict__ query,
        const float* __restrict__ Wq, const float* __restrict__ bq,
        const float* __restrict__ Wk, const float* __restrict__ bk,
        const float* __restrict__ Wv, const float* __restrict__ bv,
        const float* __restrict__ W1, const float* __restrict__ W2,
        const float* __restrict__ W3,
        unsigned short* __restrict__ WT, float* __restrict__ bcat,
        unsigned short* __restrict__ Xb) {
    __shared__ float sm[1536];
    const int bid = blockIdx.x;
    const int t = threadIdx.x;

    if (bid < PB_TR_END) {
        // WT[n][e] = W{q,k}[e][n mod 768] bf16 (q-part pre-scaled by 0.125)
        float (*tile)[33] = (float(*)[33])sm;
        const int n0 = (bid % 48) * 32, e0 = (bid / 48) * 32;
        const float* src = (n0 < 768) ? Wq : Wk;
        const float sc = (n0 < 768) ? 0.125f : 1.0f;
        const int ol0 = (n0 < 768) ? n0 : (n0 - 768);
        const int tx = t & 31, ty = t >> 5;
        #pragma unroll
        for (int s = 0; s < 4; s++)
            tile[ty + s * 8][tx] = src[(size_t)(e0 + ty + s * 8) * EDIM + ol0 + tx];
        __syncthreads();
        #pragma unroll
        for (int s = 0; s < 4; s++)
            WT[(size_t)(n0 + ty + s * 8) * EDIM + e0 + tx] = f2bf(tile[tx][ty + s * 8] * sc);
    } else if (bid < PB_VW_END) {
        // WT vw columns: WT[1536+o2][e] = sum_d Wv[e][h*64+d]*Wc[h*64+d]
        int idx = (bid - PB_TR_END) * 256 + t;   // < 27648
        int o2 = idx / 768, e = idx - o2 * 768;
        int h = o2 / 3, c = o2 - (o2 / 3) * 3;
        const float* Wc = (c == 0) ? W1 : (c == 1) ? W2 : W3;
        const float4* wvp = (const float4*)(Wv + (size_t)e * EDIM + h * HD);
        const float4* wcp = (const float4*)(Wc + h * HD);
        float s = 0.f;
        #pragma unroll
        for (int d4 = 0; d4 < 16; d4++) {
            float4 a = wvp[d4], b = wcp[d4];
            s += a.x * b.x + a.y * b.y + a.z * b.z + a.w * b.w;
        }
        WT[(size_t)(1536 + o2) * EDIM + e] = f2bf(s);
    } else if (bid < PB_CVT_END) {
        // X fp32 (n,b,e) -> Xb[m][e] bf16; 2 units per thread (half-split)
        int base = (bid - PB_VW_END) * 256 + t;   // < 196608
        #pragma unroll
        for (int half = 0; half < 2; half++) {
            int idx = base + half * 196608;
            int m = idx / 96, e8 = (idx - (idx / 96) * 96) * 8;
            int b = m >> 9, i = m & (NN - 1);
            const float* src = query + ((size_t)i * BSZ + b) * EDIM + e8;
            float4 v0 = *(const float4*)src;
            float4 v1 = *(const float4*)(src + 4);
            unsigned int p0 = f2bf(v0.x) | ((unsigned int)f2bf(v0.y) << 16);
            unsigned int p1 = f2bf(v0.z) | ((unsigned int)f2bf(v0.w) << 16);
            unsigned int p2 = f2bf(v1.x) | ((unsigned int)f2bf(v1.y) << 16);
            unsigned int p3 = f2bf(v1.z) | ((unsigned int)f2bf(v1.w) << 16);
            uint4 pk = {p0, p1, p2, p3};
            *(uint4*)&Xb[(size_t)idx * 8] = pk;
        }
    } else if (bid < PB_BC_END) {
        int o = (bid - PB_CVT_END) * 256 + t;
        if (o < NCAT) {
            float v = 0.f;
            if (o < 768) v = bq[o] * 0.125f;
            else if (o < 1536) v = bk[o - 768];
            else if (o < 1572) {
                int o2 = o - 1536;
                int h = o2 / 3, c = o2 - (o2 / 3) * 3;
                const float* Wc = (c == 0) ? W1 : (c == 1) ? W2 : W3;
                float s = 0.f;
                for (int d = 0; d < HD; d++) s += bv[h * HD + d] * Wc[h * HD + d];
                v = s;
            }
            bcat[o] = v;
        }
    } else {
        int tid = (bid - PB_BC_END) * 256 + t;
        if (tid < 8832) {
            uint4 z = {0, 0, 0, 0};
            *(uint4*)&WT[(size_t)1572 * EDIM + (size_t)tid * 8] = z;
        }
    }
}

// ---------------- K2: bf16 MFMA GEMM (128x128 tile, m97 structure, XCD-swizzled grid) ----------------
// Grid: 416 = 32 m-panels x 13 n-panels = 8 XCDs x 52. Each XCD owns 4 contiguous
// m-panels x all 13 n-panels: working set = 4x196KB (Xb rows) + 2.6MB (WT) = 3.4MB < 4MB L2.
__global__ __launch_bounds__(256) void k_gemm_qkv(
        const unsigned short* __restrict__ Xb, const unsigned short* __restrict__ WT,
        const float* __restrict__ bcat,
        unsigned short* __restrict__ qb, unsigned short* __restrict__ kb,
        float* __restrict__ vwb) {
    __shared__ short As[8 * 128 * 8];   // 16 KB  [kgroup][row][8]
    __shared__ short Bs[8 * 128 * 8];   // 16 KB
    const int t = threadIdx.x;
    const int bx = blockIdx.x;
    const int wg = (bx & 7) * 52 + (bx >> 3);        // bijective: 416 = 8*52
    const int m0 = (wg / 13) * 128, n0 = (wg % 13) * 128;
    const int w = t >> 6, lane = t & 63, quad = lane >> 4, ln = lane & 15;
    const int wr = (w & 1) * 64, wc = (w >> 1) * 64;

    f32x4 acc[4][4];
    #pragma unroll
    for (int mi = 0; mi < 4; mi++)
        #pragma unroll
        for (int ni = 0; ni < 4; ni++) acc[mi][ni] = (f32x4){0.f, 0.f, 0.f, 0.f};

    for (int k0 = 0; k0 < EDIM; k0 += 64) {
        __syncthreads();
        #pragma unroll
        for (int is = 0; is < 4; is++) {
            int slot = is * 256 + t;
            int g = slot >> 7, m = slot & 127;
            gl2lds16(Xb + (size_t)(m0 + m) * EDIM + k0 + g * 8, &As[(size_t)(is * 256 + w * 64) * 8]);
        }
        #pragma unroll
        for (int is = 0; is < 4; is++) {
            int slot = is * 256 + t;
            int g = slot >> 7, n = slot & 127;
            gl2lds16(WT + (size_t)(n0 + n) * EDIM + k0 + g * 8, &Bs[(size_t)(is * 256 + w * 64) * 8]);
        }
        __syncthreads();
        #pragma unroll
        for (int s = 0; s < 2; s++) {
            short8 af[4], bf[4];
            #pragma unroll
            for (int mi = 0; mi < 4; mi++)
                af[mi] = *(const short8*)&As[(size_t)((s * 4 + quad) * 128 + wr + mi * 16 + ln) * 8];
            #pragma unroll
            for (int ni = 0; ni < 4; ni++)
                bf[ni] = *(const short8*)&Bs[(size_t)((s * 4 + quad) * 128 + wc + ni * 16 + ln) * 8];
            #pragma unroll
            for (int mi = 0; mi < 4; mi++)
                #pragma unroll
                for (int ni = 0; ni < 4; ni++)
                    acc[mi][ni] = __builtin_amdgcn_mfma_f32_16x16x32_bf16(af[mi], bf[ni], acc[mi][ni], 0, 0, 0);
        }
    }

    #pragma unroll
    for (int mi = 0; mi < 4; mi++) {
        #pragma unroll
        for (int r = 0; r < 4; r++) {
            int mg = m0 + wr + mi * 16 + quad * 4 + r;
            int b_ = mg >> 9, i_ = mg & (NN - 1);
            #pragma unroll
            for (int ni = 0; ni < 4; ni++) {
                int o = n0 + wc + ni * 16 + ln;
                float val = acc[mi][ni][r] + bcat[o];
                if (o < 768) {
                    int h = o >> 6, d = o & 63;
                    qb[(((size_t)b_ * NH + h) * NN + i_) * HD + d] = f2bf(val);  // scale folded into WT/bcat
                } else if (o < 1536) {
                    int o2 = o - 768;
                    int h = o2 >> 6, d = o2 & 63;
                    kb[(((size_t)b_ * NH + h) * NN + i_) * HD + d] = f2bf(val);
                } else if (o < 1572) {
                    int o2 = o - 1536;
                    int h = o2 / 3, c = o2 - (o2 / 3) * 3;
                    vwb[(((size_t)b_ * NH + h) * NN + i_) * 3 + c] = val;
                }
            }
        }
    }
}

// ---------------- K3: attention partials — round-3 body + (b,h)-per-XCD block swizzle ----------------
// bid = ((q*32 + s)*8) + r, p = q*8+r = b*12+h, s = it*4+js. All 32 blocks of one
// (b,h) share blockIdx%8 -> same XCD: its kb (8x re-read) and qb (4x re-read) tiles
// stay L2-resident (12 bh-pairs x 128KB = 1.5MB < 4MB per-XCD L2).
__global__ __launch_bounds__(256, 6) void k_attn(
        const unsigned short* __restrict__ qb, const unsigned short* __restrict__ kb,
        const float* __restrict__ vwb, const float* __restrict__ bias,
        const float* __restrict__ pos,
        float* __restrict__ mp, float* __restrict__ lp,
        float* __restrict__ a0p, float* __restrict__ a1p, float* __restrict__ a2p) {
    __shared__ uint4 Ks[128 * 8];   // 16 KB, unit = row*8 + (c ^ (row&7))
    __shared__ float ws0[128], ws1[128], ws2[128];
    __shared__ float pjx[128], pjy[128], pjz[128];
    __shared__ float pix[64], piy[64], piz[64];

    const int t = threadIdx.x;
    const int bid = blockIdx.x;
    const int r_ = bid & 7;
    const int rest = bid >> 3;          // 0..383
    const int s_ = rest & 31;
    const int q_ = rest >> 5;           // 0..11
    const int p_ = q_ * 8 + r_;         // bh index 0..95
    const int b = p_ / 12;
    const int h = p_ - b * 12;
    const int it = s_ >> 2;
    const int js = s_ & 3;
    const int i0 = it * 64;
    const int jb = js * 128;
    const int w = t >> 6, lane = t & 63, quad = lane >> 4, ln = lane & 15;
    const size_t bh = (size_t)b * NH + h;

    // ---- coalesced global loads of K (128x64) tile ----
    const uint4* kg = (const uint4*)(kb + (bh * NN + jb) * HD);   // 1024 units
    const int rr = t >> 3, cc = t & 7;
    uint4 kv0 = kg[t];
    uint4 kv1 = kg[256 + t];
    uint4 kv2 = kg[512 + t];
    uint4 kv3 = kg[768 + t];
    float wv0 = vwb[bh * (NN * 3) + (size_t)jb * 3 + t];
    float wv1 = (t < 128) ? vwb[bh * (NN * 3) + (size_t)jb * 3 + 256 + t] : 0.f;

    // ---- q fragments straight from global (A-frag = 16 contiguous bytes) ----
    const unsigned short* qrow = qb + (bh * NN + i0 + w * 16 + ln) * HD;
    short8 a0f = *(const short8*)(qrow + quad * 8);
    short8 a1f = *(const short8*)(qrow + 32 + quad * 8);

    // ---- bias straight into MFMA accumulators (coalesced: 16 lanes x 4 rows) ----
    const float* bbase = bias + (bh * NN + i0 + w * 16 + quad * 4) * NN + jb + ln;
    f32x4 acc[8];
    #pragma unroll
    for (int jsub = 0; jsub < 8; jsub++)
        #pragma unroll
        for (int r = 0; r < 4; r++)
            acc[jsub][r] = bbase[r * NN + jsub * 16];

    // ---- position staging ----
    for (int idx = t; idx < 384; idx += 256) {
        float pv = pos[((size_t)b * NN + jb) * 3 + idx];
        int jj = idx / 3, c = idx - (idx / 3) * 3;
        if (c == 0) pjx[jj] = pv; else if (c == 1) pjy[jj] = pv; else pjz[jj] = pv;
    }
    if (t < 192) {
        float pv = pos[((size_t)b * NN + i0) * 3 + t];
        int ii = t / 3, c = t - (t / 3) * 3;
        if (c == 0) pix[ii] = pv; else if (c == 1) piy[ii] = pv; else piz[ii] = pv;
    }

    // ---- LDS writes (xor-swizzled) ----
    const int sw = cc ^ (rr & 7);
    Ks[rr * 8 + sw] = kv0;
    Ks[(rr + 32) * 8 + sw] = kv1;
    Ks[(rr + 64) * 8 + sw] = kv2;
    Ks[(rr + 96) * 8 + sw] = kv3;
    {
        int jj = t / 3, c = t - (t / 3) * 3;
        if (c == 0) ws0[jj] = wv0; else if (c == 1) ws1[jj] = wv0; else ws2[jj] = wv0;
        if (t < 128) {
            int t2 = 256 + t;
            int jj2 = t2 / 3, c2 = t2 - (t2 / 3) * 3;
            if (c2 == 0) ws0[jj2] = wv1; else if (c2 == 1) ws1[jj2] = wv1; else ws2[jj2] = wv1;
        }
    }
    __syncthreads();

    // ---- MFMA: D = Q·K^T ----
    #pragma unroll
    for (int jsub = 0; jsub < 8; jsub++) {
        int krow = jsub * 16 + ln;
        short8 b0f = *(const short8*)&Ks[krow * 8 + (quad ^ (krow & 7))];
        short8 b1f = *(const short8*)&Ks[krow * 8 + ((quad + 4) ^ (krow & 7))];
        acc[jsub] = __builtin_amdgcn_mfma_f32_16x16x32_bf16(a0f, b0f, acc[jsub], 0, 0, 0);
        acc[jsub] = __builtin_amdgcn_mfma_f32_16x16x32_bf16(a1f, b1f, acc[jsub], 0, 0, 0);
    }

    // ---- wave-wide max (any consistent m is valid with the exact slot merge) ----
    float m_r = acc[0][0];
    #pragma unroll
    for (int jsub = 0; jsub < 8; jsub++)
        #pragma unroll
        for (int r = 0; r < 4; r++) m_r = fmaxf(m_r, acc[jsub][r]);
    #pragma unroll
    for (int off = 1; off < 64; off <<= 1) m_r = fmaxf(m_r, __shfl_xor(m_r, off, 64));

    // ---- exp + geometry-on-the-fly weighted accumulate ----
    const int irbase = w * 16 + quad * 4;
    float lr[4] = {0.f, 0.f, 0.f, 0.f};
    float A0[4] = {0.f, 0.f, 0.f, 0.f};
    float A1[4] = {0.f, 0.f, 0.f, 0.f};
    float A2[4] = {0.f, 0.f, 0.f, 0.f};
    #pragma unroll
    for (int jsub = 0; jsub < 8; jsub++) {
        const int jl = jsub * 16 + ln;
        float w0 = ws0[jl], w1 = ws1[jl], w2 = ws2[jl];
        float px = pjx[jl], py = pjy[jl], pz = pjz[jl];
        #pragma unroll
        for (int r = 0; r < 4; r++) {
            float dx = px - pix[irbase + r];
            float dy = py - piy[irbase + r];
            float dz = pz - piz[irbase + r];
            float d2 = fmaf(dx, dx, fmaf(dy, dy, dz * dz));
            float inv = __builtin_amdgcn_rcpf(__builtin_amdgcn_sqrtf(d2) + 1e-5f);
            float p = __expf(acc[jsub][r] - m_r);
            float pi = p * inv;
            lr[r] += p;
            A0[r] = fmaf(pi * dx, w0, A0[r]);
            A1[r] = fmaf(pi * dy, w1, A1[r]);
            A2[r] = fmaf(pi * dz, w2, A2[r]);
        }
    }

    // ---- reduce over ln (j) ----
    #pragma unroll
    for (int off = 1; off < 16; off <<= 1) {
        #pragma unroll
        for (int r = 0; r < 4; r++) {
            lr[r] += __shfl_xor(lr[r], off, 64);
            A0[r] += __shfl_xor(A0[r], off, 64);
            A1[r] += __shfl_xor(A1[r], off, 64);
            A2[r] += __shfl_xor(A2[r], off, 64);
        }
    }
    if (ln == 0) {
        #pragma unroll
        for (int r = 0; r < 4; r++) {
            int ig = i0 + irbase + r;
            size_t o4 = (bh * NN + ig) * 4 + js;
            mp[o4] = m_r; lp[o4] = lr[r];
            a0p[o4] = A0[r]; a1p[o4] = A1[r]; a2p[o4] = A2[r];
        }
    }
}

// ---------------- K4: finalize — thread per (b,i,h), LDS head-reduce, 256 blocks ----------------
__global__ __launch_bounds__(256) void k_finalize(
        const float* __restrict__ mp, const float* __restrict__ lp,
        const float* __restrict__ a0p, const float* __restrict__ a1p,
        const float* __restrict__ a2p,
        const float* __restrict__ b1, const float* __restrict__ b2,
        const float* __restrict__ b3, float* __restrict__ out) {
    __shared__ float red[NH][16][3];
    const int t = threadIdx.x;
    const int g0 = blockIdx.x * 16;        // 16 (b,i) rows per block
    const int b = g0 >> 9;
    const int i0 = g0 & (NN - 1);

    if (t < NH * 16) {
        int h = t >> 4, row = t & 15;      // consecutive t -> consecutive rows (coalesced)
        size_t base = (((size_t)b * NH + h) * NN + i0 + row) * 4;
        f32x4 mv = *(const f32x4*)&mp[base];
        f32x4 lv = *(const f32x4*)&lp[base];
        f32x4 A0 = *(const f32x4*)&a0p[base];
        f32x4 A1 = *(const f32x4*)&a1p[base];
        f32x4 A2 = *(const f32x4*)&a2p[base];
        float M = fmaxf(fmaxf(mv[0], mv[1]), fmaxf(mv[2], mv[3]));
        float L = 0.f, c0 = 0.f, c1 = 0.f, c2 = 0.f;
        #pragma unroll
        for (int js = 0; js < 4; js++) {
            float e = __expf(mv[js] - M);
            L = fmaf(e, lv[js], L);
            c0 = fmaf(e, A0[js], c0);
            c1 = fmaf(e, A1[js], c1);
            c2 = fmaf(e, A2[js], c2);
        }
        float inv = 1.f / L;
        red[h][row][0] = c0 * inv;
        red[h][row][1] = c1 * inv;
        red[h][row][2] = c2 * inv;
    }
    __syncthreads();
    if (t < 48) {
        int row = t / 3, c = t - row * 3;
        float s = 0.f;
        #pragma unroll
        for (int h = 0; h < NH; h++) s += red[h][row][c];
        const float* bb = (c == 0) ? b1 : (c == 1) ? b2 : b3;
        out[((size_t)g0 + row) * 3 + c] = s + bb[0];
    }
}

extern "C" void kernel_launch(void* const* d_in, const int* in_sizes, int n_in,
                              void* d_out, int out_size, void* d_ws, size_t ws_size,
                              hipStream_t stream) {
    const float* query = (const float*)d_in[0];
    const float* bias  = (const float*)d_in[1];
    const float* pos   = (const float*)d_in[2];
    const float* Wq = (const float*)d_in[3];
    const float* bq = (const float*)d_in[4];
    const float* Wk = (const float*)d_in[5];
    const float* bk = (const float*)d_in[6];
    const float* Wv = (const float*)d_in[7];
    const float* bv = (const float*)d_in[8];
    const float* W1 = (const float*)d_in[9];
    const float* b1 = (const float*)d_in[10];
    const float* W2 = (const float*)d_in[11];
    const float* b2 = (const float*)d_in[12];
    const float* W3 = (const float*)d_in[13];
    const float* b3 = (const float*)d_in[14];
    float* out = (float*)d_out;

    char* p = (char*)d_ws;
    unsigned short* WT = (unsigned short*)p; p += (size_t)NCAT * EDIM * 2;      // 2.6 MB
    float* bcat = (float*)p;                 p += (size_t)NCAT * 4;
    unsigned short* Xb = (unsigned short*)p; p += (size_t)BSZ * NN * EDIM * 2;  // 6.3 MB
    unsigned short* qb = (unsigned short*)p; p += (size_t)BSZ * NH * NN * HD * 2;
    unsigned short* kb = (unsigned short*)p; p += (size_t)BSZ * NH * NN * HD * 2;
    float* vwb = (float*)p;                  p += (size_t)BSZ * NH * NN * 3 * 4;
    const size_t PSZ = (size_t)BSZ * NH * NN * 4;   // partial slots (b,h,i,js)
    float* mp  = (float*)p; p += PSZ * 4;
    float* lp  = (float*)p; p += PSZ * 4;
    float* a0p = (float*)p; p += PSZ * 4;
    float* a1p = (float*)p; p += PSZ * 4;
    float* a2p = (float*)p; p += PSZ * 4;

    k_prep<<<PREP_BLOCKS, 256, 0, stream>>>(query, Wq, bq, Wk, bk, Wv, bv,
                                            W1, W2, W3, WT, bcat, Xb);
    k_gemm_qkv<<<416, 256, 0, stream>>>(Xb, WT, bcat, qb, kb, vwb);
    k_attn<<<BSZ * NH * 8 * 4, 256, 0, stream>>>(qb, kb, vwb, bias, pos,
                                                 mp, lp, a0p, a1p, a2p);
    k_finalize<<<BSZ * NN / 16, 256, 0, stream>>>(mp, lp, a0p, a1p, a2p, b1, b2, b3, out);
}